// Round 7
// baseline (133.756 us; speedup 1.0000x reference)
//
#include <hip/hip_runtime.h>
#include <math.h>

// Problem constants (from reference setup_inputs)
#define BS 64      // batch
#define F  256     // features (K of the Gram matmul)
#define M  128     // columns  (M=N of the Gram matmul)
#define MF (M * F) // u16 elements per matrix in hT
#define NT2 528    // 2x2 row-pair tiles per mat (32*33/2); grid = 1056

typedef unsigned short u16;
typedef _Float16 f16x8 __attribute__((ext_vector_type(8)));
typedef float    f32x16 __attribute__((ext_vector_type(16)));

typedef const __attribute__((address_space(1))) void gas_t;
typedef __attribute__((address_space(3))) void las_t;

// ---------------------------------------------------------------------------
// Pre-pass: fp32 [f][m] -> fp16 GRANULE-MAJOR hT[b][f8][m][8]. (round 6:
// coalesced staging worth 107->58 us; layout verified.)
// ---------------------------------------------------------------------------
__global__ __launch_bounds__(256) void convert_f16_kernel(
    const float* __restrict__ m1, const float* __restrict__ m2,
    u16* __restrict__ hT)
{
    __shared__ float tile[64 * M];   // 32 KB
    const int mat = blockIdx.x >> 6;
    const int b   = blockIdx.x & 63;
    const int f0  = blockIdx.y * 64;
    const float* src = (mat == 0 ? m1 : m2) + (size_t)b * MF + (size_t)f0 * M;
    const int tid = threadIdx.x;

    const float4* g = (const float4*)src;
    float4* s = (float4*)tile;
    #pragma unroll
    for (int i = 0; i < 8; ++i)
        s[tid + i * 256] = g[tid + i * 256];
    __syncthreads();

    const size_t obase = ((size_t)(mat * BS + b) * 32 + (f0 >> 3)) * 1024;
    #pragma unroll
    for (int it = 0; it < 4; ++it) {
        const int idx = it * 256 + tid;
        const int f8l = idx >> 7;
        const int m   = idx & 127;
        u16 hh[8] __attribute__((aligned(16)));
        #pragma unroll
        for (int j = 0; j < 8; ++j) {
            const float x = tile[(f8l * 8 + j) * M + m];  // 2 lanes/bank: free
            const _Float16 h = (_Float16)x;               // RNE
            hh[j] = __builtin_bit_cast(u16, h);
        }
        *(uint4*)&hT[obase + (size_t)idx * 8] = *(const uint4*)hh;
    }
}

// ---------------------------------------------------------------------------
// ROUND 15. r14 falsified the L3-service theory: XCD pinning cut HBM FETCH
// 2.5x (hT L2-resident per XCD) yet time was byte-identical (53.4 vs 53.0).
// Surviving model across r9-r14: a per-CU VMEM issue/return cap (~12-15
// B/cyc/CU, invariant to hit level) -> time ~ VMEM instruction count ~
// bytes requested. The one untested lever at fixed-or-better occupancy is
// BYTE VOLUME.
// THIS ROUND: 2x2 super-tile (4 Gram matrices from 4 staged rows): 405 ->
// 270 MB global (-33% bytes AND -33% VMEM instrs), with occupancy UP:
// 1024T blocks, 16 waves, wave (m = w>>2, quadrant q = w&3) owns a 64x64
// quarter of matrix m -> acc = 4 x f32x16 = 64 AGPR, <=128 regs/wave
// (__launch_bounds__(1024,4)) -> 4 waves/SIMD (2x r9; fixes r13's
// 1-block/2-wave trap). Staging via global_load_lds (wave-uniform dest +
// lane*16B -- exactly the DMA pattern; no VGPR round-trip, no ds_writes;
// m151: gload_lds 874 vs reg-staging 646 TF). K=32 slices, double-buffered
// A+B rows = 64 KB LDS. XCD pinning kept (1056 = 8*132, bijective).
// Exact 2x2 coverage of 64 rows: no invalid-pair edge case. Diagonal tiles
// (ta==tb) compute transpose twins -> byte-identical double-writes, benign
// (verified passing in r13).
// Read-out: gram >= 50 us kills the volume theory -> structural; pivot to
// ablation probe next.
// ---------------------------------------------------------------------------

// Stage one K=32 slice of this wave's 2 chunks (1 KB each) via DMA.
// chunk k = w*2 + i: row r_s = k>>3 (0..3 -> A1,A2,B1,B2), j = k&7.
#define GLOAD(S, BUF) {                                                       \
    const u16* g0 = srow + (S) * 4096 + j0 * 512 + lane * 8;                  \
    const u16* g1 = srow + (S) * 4096 + j1 * 512 + lane * 8;                  \
    __builtin_amdgcn_global_load_lds((gas_t*)g0,                              \
        (las_t*)&lds[ldst0 + (BUF)], 16, 0, 0);                               \
    __builtin_amdgcn_global_load_lds((gas_t*)g1,                              \
        (las_t*)&lds[ldst1 + (BUF)], 16, 0, 0);                               \
}

// One K=32 slice: kk=0,1; per kk: 2 A-frags + 2 B-frags (ds_read_b128), 4 MFMA.
#define MFMA_SLICE(BUF) {                                                     \
    __builtin_amdgcn_s_setprio(1);                                            \
    _Pragma("unroll")                                                         \
    for (int kk = 0; kk < 2; ++kk) {                                          \
        const int ab = ra * 8192 + (BUF) + kk * 2048 + aoffb;                 \
        const int bb = rb * 8192 + (BUF) + kk * 2048 + boffb;                 \
        const f16x8 a0 = *(const f16x8*)&lds[ab];                             \
        const f16x8 a1 = *(const f16x8*)&lds[ab + 256];                       \
        const f16x8 b0 = *(const f16x8*)&lds[bb];                             \
        const f16x8 b1 = *(const f16x8*)&lds[bb + 256];                       \
        acc[0][0] = __builtin_amdgcn_mfma_f32_32x32x16_f16(a0, b0, acc[0][0], 0, 0, 0); \
        acc[0][1] = __builtin_amdgcn_mfma_f32_32x32x16_f16(a0, b1, acc[0][1], 0, 0, 0); \
        acc[1][0] = __builtin_amdgcn_mfma_f32_32x32x16_f16(a1, b0, acc[1][0], 0, 0, 0); \
        acc[1][1] = __builtin_amdgcn_mfma_f32_32x32x16_f16(a1, b1, acc[1][1], 0, 0, 0); \
    }                                                                         \
    __builtin_amdgcn_s_setprio(0);                                            \
}

__global__ __launch_bounds__(1024, 4) void gram_hist_mfma(
    const u16* __restrict__ hT, float* __restrict__ out)
{
    // [row 0..3][buf 0..1][4096 u16] = 64 KB. rows: 0=A1,1=A2,2=B1,3=B2.
    __shared__ u16 lds[4 * 2 * 4096];
    __shared__ float smin[16], smax[16];
    __shared__ int hist[4][8];

    const int tid  = threadIdx.x;
    const int lane = tid & 63;
    const int w    = tid >> 6;       // 0..15

    if (tid < 32) hist[tid >> 3][tid & 7] = 0;

    // XCD pinning: 1056 = 8 * 132. xcd = bid & 7 (HW round-robin);
    // mats split 4+4 XCDs; slot = (xcd&3)*132 + bid>>3 in [0,528).
    const int bid = blockIdx.x;
    const int xcd = bid & 7;
    const int mat = xcd >> 2;
    int p = (xcd & 3) * 132 + (bid >> 3);
    // decode p -> (ta, tb), ta-major upper triangle of 32 row-pair groups
    int ta = 0;
    { int cnt = 32; while (p >= cnt) { p -= cnt; ++ta; cnt = 32 - ta; } }
    const int tb = ta + p;

    const int m  = w >> 2;           // matrix 0..3: rows (2ta+(m>>1), 2tb+(m&1))
    const int q  = w & 3;            // quadrant
    const int qr = q >> 1;           // 64-row half
    const int qc = q & 1;            // 64-col half
    const int l31   = lane & 31;
    const int lhalf = lane >> 5;

    // Staging chunk assignment (wave-uniform LDS dest, per-lane global src).
    const int k0  = w * 2;           // chunks k0, k0+1 (same row)
    const int r_s = k0 >> 3;         // staged row 0..3
    const int rowsel = (r_s < 2) ? (2 * ta + r_s) : (2 * tb + (r_s - 2));
    const u16* srow = hT + (size_t)(mat * BS + rowsel) * MF;
    const int j0 = k0 & 7, j1 = (k0 + 1) & 7;
    const int ldst0 = r_s * 8192 + j0 * 512;   // u16 units, + buf at use
    const int ldst1 = r_s * 8192 + j1 * 512;

    // Fragment bases (u16 units).
    const int ra = m >> 1;           // A row slot 0/1
    const int rb = 2 + (m & 1);      // B row slot 2/3
    const int aoffb = lhalf * 1024 + qr * 512 + l31 * 8;
    const int boffb = lhalf * 1024 + qc * 512 + l31 * 8;

    f32x16 acc[2][2];
    #pragma unroll
    for (int t = 0; t < 2; ++t)
        #pragma unroll
        for (int u = 0; u < 2; ++u)
            #pragma unroll
            for (int r = 0; r < 16; ++r) acc[t][u][r] = 0.0f;

    // ---- prologue: slice 0 -> buf0 (latency exposed once) ----
    GLOAD(0, 0);
    __syncthreads();   // compiler drains vmcnt -> DMA landed

    // ---- 8 slices, double-buffered, 1-ahead DMA prefetch ----
    #pragma unroll
    for (int s = 0; s < 8; ++s) {
        const int cur = (s & 1) * 4096;
        const int alt = cur ^ 4096;
        if (s < 7) GLOAD(s + 1, alt);   // latency hidden by this slice's MFMAs
        MFMA_SLICE(cur);
        __syncthreads();                 // drain = exactly the wait we need
    }

    // ---- epilogue: matrix m owned by waves 4m..4m+3 ----
    float vmin = acc[0][0][0], vmax = vmin;
    #pragma unroll
    for (int t = 0; t < 2; ++t)
        #pragma unroll
        for (int u = 0; u < 2; ++u)
            #pragma unroll
            for (int r = 0; r < 16; ++r) {
                vmin = fminf(vmin, acc[t][u][r]);
                vmax = fmaxf(vmax, acc[t][u][r]);
            }
    #pragma unroll
    for (int off = 1; off < 64; off <<= 1) {
        vmin = fminf(vmin, __shfl_xor(vmin, off, 64));
        vmax = fmaxf(vmax, __shfl_xor(vmax, off, 64));
    }
    if (lane == 0) { smin[w] = vmin; smax[w] = vmax; }
    __syncthreads();
    const int m4 = m * 4;
    const float pmn = fminf(fminf(smin[m4], smin[m4 + 1]),
                            fminf(smin[m4 + 2], smin[m4 + 3]));
    const float pmx = fmaxf(fmaxf(smax[m4], smax[m4 + 1]),
                            fmaxf(smax[m4 + 2], smax[m4 + 3]));
    const float denom = (pmx > pmn) ? (pmx - pmn) : 1.0f;
    const float scale = 8.0f / denom;
    const float bias  = -pmn * scale;

    // per-thread packed histogram: 64 values -> 8-bit fields (<=64/bin)
    unsigned w0 = 0, w1 = 0;
    #pragma unroll
    for (int t = 0; t < 2; ++t)
        #pragma unroll
        for (int u = 0; u < 2; ++u)
            #pragma unroll
            for (int r = 0; r < 16; ++r) {
                const float tv = fmaf(acc[t][u][r], scale, bias);
                int k = (int)tv;         // tv >= -eps; trunc == floor
                k = k > 7 ? 7 : k;
                const unsigned inc = 1u << ((k & 3) * 8);
                if (k < 4) w0 += inc; else w1 += inc;
            }
    unsigned e0 = (w0 & 0xFFu)         | (((w0 >> 8)  & 0xFFu) << 16);
    unsigned e1 = ((w0 >> 16) & 0xFFu) | (((w0 >> 24) & 0xFFu) << 16);
    unsigned e2 = (w1 & 0xFFu)         | (((w1 >> 8)  & 0xFFu) << 16);
    unsigned e3 = ((w1 >> 16) & 0xFFu) | (((w1 >> 24) & 0xFFu) << 16);
    #pragma unroll
    for (int off = 32; off > 0; off >>= 1) {
        e0 += __shfl_down(e0, off, 64);
        e1 += __shfl_down(e1, off, 64);
        e2 += __shfl_down(e2, off, 64);
        e3 += __shfl_down(e3, off, 64);
    }
    if (lane == 0) {
        atomicAdd(&hist[m][0], (int)(e0 & 0xFFFFu)); atomicAdd(&hist[m][1], (int)(e0 >> 16));
        atomicAdd(&hist[m][2], (int)(e1 & 0xFFFFu)); atomicAdd(&hist[m][3], (int)(e1 >> 16));
        atomicAdd(&hist[m][4], (int)(e2 & 0xFFFFu)); atomicAdd(&hist[m][5], (int)(e2 >> 16));
        atomicAdd(&hist[m][6], (int)(e3 & 0xFFFFu)); atomicAdd(&hist[m][7], (int)(e3 >> 16));
    }
    __syncthreads();

    // q==0 wave of each matrix normalizes and writes both symmetric rows.
    if (q == 0 && lane < 8) {
        float ss = 0.0f;
        #pragma unroll
        for (int k = 0; k < 8; ++k) {
            const float cc = (float)hist[m][k];
            ss += cc * cc;
        }
        const float nrm = fmaxf(sqrtf(ss), 1e-12f);
        const float v = (float)hist[m][lane] / nrm;
        const int A = 2 * ta + (m >> 1);
        const int B = 2 * tb + (m & 1);
        out[((size_t)A * BS + B) * 16 + mat * 8 + lane] = v;
        if (A != B)
            out[((size_t)B * BS + A) * 16 + mat * 8 + lane] = v;
    }
}

extern "C" void kernel_launch(void* const* d_in, const int* in_sizes, int n_in,
                              void* d_out, int out_size, void* d_ws, size_t ws_size,
                              hipStream_t stream) {
    const float* m1 = (const float*)d_in[0];
    const float* m2 = (const float*)d_in[1];
    float* out = (float*)d_out;

    // Workspace: granule-major fp16 array, 2*64*128*256 u16 = 8.39 MB.
    u16* hT = (u16*)d_ws;

    convert_f16_kernel<<<dim3(128, 4), 256, 0, stream>>>(m1, m2, hT);
    gram_hist_mfma<<<2 * NT2, 1024, 0, stream>>>(hT, out);
}

// Round 8
// 119.302 us; speedup vs baseline: 1.1212x; 1.1212x over previous
//
#include <hip/hip_runtime.h>
#include <math.h>

// Problem constants (from reference setup_inputs)
#define BS 64      // batch
#define F  256     // features (K of the Gram matmul)
#define M  128     // columns  (M=N of the Gram matmul)
#define MF (M * F) // u16 elements per matrix in hT
#define NBP 1056   // tiles per mat: sum_a ceil((64-a)/2)

typedef unsigned short u16;
typedef _Float16 f16x8 __attribute__((ext_vector_type(8)));
typedef float    f32x16 __attribute__((ext_vector_type(16)));

// ---------------------------------------------------------------------------
// Pre-pass: fp32 [f][m] -> fp16 GRANULE-MAJOR hT[b][f8][m][8].
// ---------------------------------------------------------------------------
__global__ __launch_bounds__(256) void convert_f16_kernel(
    const float* __restrict__ m1, const float* __restrict__ m2,
    u16* __restrict__ hT)
{
    __shared__ float tile[64 * M];   // 32 KB
    const int mat = blockIdx.x >> 6;
    const int b   = blockIdx.x & 63;
    const int f0  = blockIdx.y * 64;
    const float* src = (mat == 0 ? m1 : m2) + (size_t)b * MF + (size_t)f0 * M;
    const int tid = threadIdx.x;

    const float4* g = (const float4*)src;
    float4* s = (float4*)tile;
    #pragma unroll
    for (int i = 0; i < 8; ++i)
        s[tid + i * 256] = g[tid + i * 256];
    __syncthreads();

    const size_t obase = ((size_t)(mat * BS + b) * 32 + (f0 >> 3)) * 1024;
    #pragma unroll
    for (int it = 0; it < 4; ++it) {
        const int idx = it * 256 + tid;
        const int f8l = idx >> 7;
        const int m   = idx & 127;
        u16 hh[8] __attribute__((aligned(16)));
        #pragma unroll
        for (int j = 0; j < 8; ++j) {
            const float x = tile[(f8l * 8 + j) * M + m];  // 2 lanes/bank: free
            const _Float16 h = (_Float16)x;               // RNE
            hh[j] = __builtin_bit_cast(u16, h);
        }
        *(uint4*)&hT[obase + (size_t)idx * 8] = *(const uint4*)hh;
    }
}

// ---------------------------------------------------------------------------
// ROUND 16: COUNTED-VMCNT, NON-DRAINING PIPELINE (T4). Unified model fitting
// r9-r15: global-load rate = outstanding-bytes-per-CU / latency (Little).
// Every prior kernel drained vmcnt to 0 each chunk (__syncthreads emits
// s_waitcnt vmcnt(0) before s_barrier) -> avg ~3KB/wave in flight -> 7.6
// TB/s. r10 accidentally raised outstanding 1.67x -> rate 1.46x (11.1 TB/s)
// -- the only rate change ever observed, and it tracked OUTSTANDING.
// THIS ROUND: r14 kernel (best, 53.4 us) with (a) B-fragment register ring
// depth 3 + A register-prefetch depth 2 over a 3-buffer LDS ring, and (b)
// main-loop barriers = raw s_barrier preceded by s_waitcnt lgkmcnt(0) ONLY
// (ds-write visibility) -- vmcnt is NEVER drained; the compiler's own
// dependency waits are counted (vmcnt(10) at the A ds_write; FIFO analysis:
// steady outstanding 10-16 loads/wave = ~96KB/CU, ~4x r14's average).
// sched_barrier(0) after s_barrier pins code motion (rule 18). All ring
// indices compile-time constants (rule 20). Regs: 128 AGPR + ~105 VGPR
// <= 256 -> 2 waves/SIMD, 2 blocks/CU preserved. XCD pinning kept.
// ---------------------------------------------------------------------------

#define KBAR() {                                              \
    asm volatile("s_waitcnt lgkmcnt(0)" ::: "memory");        \
    __builtin_amdgcn_s_barrier();                             \
    __builtin_amdgcn_sched_barrier(0);                        \
}

#define LOADB_S(SLOT, CH) {                                   \
    const u16* pbk = pb + (CH) * 4096;                        \
    bF[SLOT][0][0] = *(const f16x8*)(pbk);                    \
    bF[SLOT][0][1] = *(const f16x8*)(pbk + 256);              \
    bF[SLOT][1][0] = *(const f16x8*)(pbk + 2048);             \
    bF[SLOT][1][1] = *(const f16x8*)(pbk + 2048 + 256);       \
}

// Chunk C: MFMA on LDS buf C%3 + bF[C%3]; A(C+2)->regs at top; B(C+3) into
// the just-freed slot after the cluster; A(C+1) regs -> LDS buf (C+1)%3 at
// the end; counted-vmcnt barrier. All guards/indices fold at compile time.
#define CHUNK(C) {                                                            \
    if ((C) <= 5) {                                                           \
        rA[(C) & 1][0] = *(const uint4*)(pa + ((C) + 2) * 4096);              \
        rA[(C) & 1][1] = *(const uint4*)(pa + ((C) + 2) * 4096 + 2048);       \
    }                                                                         \
    {                                                                         \
        const int cb = ((C) % 3) * 4096;                                      \
        _Pragma("unroll")                                                     \
        for (int kk = 0; kk < 2; ++kk) {                                      \
            const int base = cb + kk * 2048 + lhalf * 1024 + l31 * 8;         \
            f16x8 af[4];                                                      \
            _Pragma("unroll")                                                 \
            for (int t = 0; t < 4; ++t)                                       \
                af[t] = *(const f16x8*)&lds[base + t * 256];                  \
            _Pragma("unroll")                                                 \
            for (int ti = 0; ti < 4; ++ti) {                                  \
                acc[ti][0] = __builtin_amdgcn_mfma_f32_32x32x16_f16(af[ti], bF[(C) % 3][kk][0], acc[ti][0], 0, 0, 0); \
                acc[ti][1] = __builtin_amdgcn_mfma_f32_32x32x16_f16(af[ti], bF[(C) % 3][kk][1], acc[ti][1], 0, 0, 0); \
            }                                                                 \
        }                                                                     \
    }                                                                         \
    if ((C) <= 4) LOADB_S((C) % 3, (C) + 3);                                  \
    if ((C) <= 6) {                                                           \
        const int nb = (((C) + 1) % 3) * 4096;                                \
        *(uint4*)&lds[nb + d0] = rA[((C) + 1) & 1][0];                        \
        *(uint4*)&lds[nb + d1] = rA[((C) + 1) & 1][1];                        \
        KBAR();                                                               \
    }                                                                         \
}

__global__ __launch_bounds__(256, 2) void gram_hist_mfma(
    const u16* __restrict__ hT, float* __restrict__ out)
{
    __shared__ u16 lds[3 * 4096];   // 24 KB: A chunk ring (3 x 8 KB)
    __shared__ float smin[4], smax[4];
    __shared__ int hist[2][8];

    const int tid  = threadIdx.x;
    const int lane = tid & 63;
    const int w    = tid >> 6;

    if (tid < 16) hist[tid >> 3][tid & 7] = 0;

    // XCD-pinned mapping: 2112 blocks, 8 XCDs x 264 slots (r14: cut HBM 2.5x).
    const int bid  = blockIdx.x;
    const int xcd  = bid & 7;
    const int mat  = xcd >> 2;
    int p = (xcd & 3) * 264 + (bid >> 3);
    // Decode tile p -> (a, pair) with per-a count ceil((64-a)/2).
    int a = 0;
    { int cnt = 32; while (p >= cnt) { p -= cnt; ++a; cnt = (64 - a + 1) >> 1; } }
    const int b1 = a + 2 * p;
    int b2 = b1 + 1;
    const bool b2valid = (b2 <= 63);
    if (!b2valid) b2 = b1;          // duplicate work, writes suppressed

    const int pp = w >> 1;     // which pair (0: b1, 1: b2)
    const int c  = w & 1;      // which 64-col half
    const int l31   = lane & 31;
    const int lhalf = lane >> 5;

    // A staging: two uint4 per thread per chunk.
    const u16* pa = hT + (size_t)(mat * BS + a) * MF + tid * 8;
    const int d0 = tid * 8;            // A, first 256 granules
    const int d1 = (256 + tid) * 8;    // A, second

    // B fragment per-lane global base (u16 units).
    const int bsel = pp ? b2 : b1;
    const u16* pb = hT + (size_t)(mat * BS + bsel) * MF
                  + (size_t)(lhalf * 1024 + c * 512 + l31 * 8);

    f32x16 acc[4][2];
    #pragma unroll
    for (int ti = 0; ti < 4; ++ti)
        #pragma unroll
        for (int u = 0; u < 2; ++u)
            #pragma unroll
            for (int r = 0; r < 16; ++r) acc[ti][u][r] = 0.0f;

    uint4 rA[2][2];            // A register-prefetch, depth 2 (static idx)
    f16x8 bF[3][2][2];         // B fragment ring, depth 3 (static idx)

    // ---- prologue: A(0),A(1) -> regs FIRST (so their ds_write wait is
    // counted, not draining), then B(0..2) ring fill; A(0) -> buf0 ----
    rA[0][0] = *(const uint4*)(pa);
    rA[0][1] = *(const uint4*)(pa + 2048);
    rA[1][0] = *(const uint4*)(pa + 4096);
    rA[1][1] = *(const uint4*)(pa + 4096 + 2048);
    LOADB_S(0, 0);
    LOADB_S(1, 1);
    LOADB_S(2, 2);
    *(uint4*)&lds[d0] = rA[0][0];   // compiler: vmcnt(14) -- non-draining
    *(uint4*)&lds[d1] = rA[0][1];
    KBAR();

    // ---- 8 chunks, fully static ----
    CHUNK(0); CHUNK(1); CHUNK(2); CHUNK(3);
    CHUNK(4); CHUNK(5); CHUNK(6); CHUNK(7);

    // ---- epilogue: pair pp owned by waves (pp,c=0),(pp,c=1) ----
    float vmin = acc[0][0][0], vmax = vmin;
    #pragma unroll
    for (int ti = 0; ti < 4; ++ti)
        #pragma unroll
        for (int u = 0; u < 2; ++u)
            #pragma unroll
            for (int r = 0; r < 16; ++r) {
                vmin = fminf(vmin, acc[ti][u][r]);
                vmax = fmaxf(vmax, acc[ti][u][r]);
            }
    #pragma unroll
    for (int off = 1; off < 64; off <<= 1) {
        vmin = fminf(vmin, __shfl_xor(vmin, off, 64));
        vmax = fmaxf(vmax, __shfl_xor(vmax, off, 64));
    }
    if (lane == 0) { smin[w] = vmin; smax[w] = vmax; }
    __syncthreads();
    const float pmn = fminf(smin[pp * 2], smin[pp * 2 + 1]);
    const float pmx = fmaxf(smax[pp * 2], smax[pp * 2 + 1]);
    const float denom = (pmx > pmn) ? (pmx - pmn) : 1.0f;
    const float scale = 8.0f / denom;
    const float bias  = -pmn * scale;

    // per-thread packed histogram: 128 values -> 8-bit fields (<=128/bin)
    unsigned w0 = 0, w1 = 0;
    #pragma unroll
    for (int ti = 0; ti < 4; ++ti)
        #pragma unroll
        for (int u = 0; u < 2; ++u)
            #pragma unroll
            for (int r = 0; r < 16; ++r) {
                const float t = fmaf(acc[ti][u][r], scale, bias);
                int k = (int)t;          // t >= -eps; trunc == floor
                k = k > 7 ? 7 : k;
                const unsigned inc = 1u << ((k & 3) * 8);
                if (k < 4) w0 += inc; else w1 += inc;
            }
    unsigned e0 = (w0 & 0xFFu)         | (((w0 >> 8)  & 0xFFu) << 16);
    unsigned e1 = ((w0 >> 16) & 0xFFu) | (((w0 >> 24) & 0xFFu) << 16);
    unsigned e2 = (w1 & 0xFFu)         | (((w1 >> 8)  & 0xFFu) << 16);
    unsigned e3 = ((w1 >> 16) & 0xFFu) | (((w1 >> 24) & 0xFFu) << 16);
    #pragma unroll
    for (int off = 32; off > 0; off >>= 1) {
        e0 += __shfl_down(e0, off, 64);
        e1 += __shfl_down(e1, off, 64);
        e2 += __shfl_down(e2, off, 64);
        e3 += __shfl_down(e3, off, 64);
    }
    if (lane == 0) {
        atomicAdd(&hist[pp][0], (int)(e0 & 0xFFFFu)); atomicAdd(&hist[pp][1], (int)(e0 >> 16));
        atomicAdd(&hist[pp][2], (int)(e1 & 0xFFFFu)); atomicAdd(&hist[pp][3], (int)(e1 >> 16));
        atomicAdd(&hist[pp][4], (int)(e2 & 0xFFFFu)); atomicAdd(&hist[pp][5], (int)(e2 >> 16));
        atomicAdd(&hist[pp][6], (int)(e3 & 0xFFFFu)); atomicAdd(&hist[pp][7], (int)(e3 >> 16));
    }
    __syncthreads();

    // one wave per pair normalizes and writes both symmetric rows
    const int B = (pp == 0) ? b1 : b2;
    const bool valid = (pp == 0) || b2valid;
    if (valid && c == 0 && lane < 8) {
        float ss = 0.0f;
        #pragma unroll
        for (int k = 0; k < 8; ++k) {
            const float cc = (float)hist[pp][k];
            ss += cc * cc;
        }
        const float nrm = fmaxf(sqrtf(ss), 1e-12f);
        const float v = (float)hist[pp][lane] / nrm;
        out[((size_t)a * BS + B) * 16 + mat * 8 + lane] = v;
        if (a != B)
            out[((size_t)B * BS + a) * 16 + mat * 8 + lane] = v;
    }
}

extern "C" void kernel_launch(void* const* d_in, const int* in_sizes, int n_in,
                              void* d_out, int out_size, void* d_ws, size_t ws_size,
                              hipStream_t stream) {
    const float* m1 = (const float*)d_in[0];
    const float* m2 = (const float*)d_in[1];
    float* out = (float*)d_out;

    // Workspace: granule-major fp16 array, 2*64*128*256 u16 = 8.39 MB.
    u16* hT = (u16*)d_ws;

    convert_f16_kernel<<<dim3(128, 4), 256, 0, stream>>>(m1, m2, hT);
    gram_hist_mfma<<<2 * NBP, 256, 0, stream>>>(hT, out);
}

// Round 9
// 119.257 us; speedup vs baseline: 1.1216x; 1.0004x over previous
//
#include <hip/hip_runtime.h>
#include <math.h>

// Problem constants (from reference setup_inputs)
#define BS 64      // batch
#define F  256     // features (K of the Gram matmul)
#define M  128     // columns  (M=N of the Gram matmul)
#define MF (M * F) // u16 elements per matrix in hT
#define NPAIR 2080 // (a,b) pairs per mat, a<=b: 64*65/2; grid = 4160 = 8*520

typedef unsigned short u16;
typedef _Float16 f16x8 __attribute__((ext_vector_type(8)));
typedef float    f32x16 __attribute__((ext_vector_type(16)));

// ---------------------------------------------------------------------------
// Pre-pass: fp32 [f][m] -> fp16 GRANULE-MAJOR hT[b][f8][m][8].
// ---------------------------------------------------------------------------
__global__ __launch_bounds__(256) void convert_f16_kernel(
    const float* __restrict__ m1, const float* __restrict__ m2,
    u16* __restrict__ hT)
{
    __shared__ float tile[64 * M];   // 32 KB
    const int mat = blockIdx.x >> 6;
    const int b   = blockIdx.x & 63;
    const int f0  = blockIdx.y * 64;
    const float* src = (mat == 0 ? m1 : m2) + (size_t)b * MF + (size_t)f0 * M;
    const int tid = threadIdx.x;

    const float4* g = (const float4*)src;
    float4* s = (float4*)tile;
    #pragma unroll
    for (int i = 0; i < 8; ++i)
        s[tid + i * 256] = g[tid + i * 256];
    __syncthreads();

    const size_t obase = ((size_t)(mat * BS + b) * 32 + (f0 >> 3)) * 1024;
    #pragma unroll
    for (int it = 0; it < 4; ++it) {
        const int idx = it * 256 + tid;
        const int f8l = idx >> 7;
        const int m   = idx & 127;
        u16 hh[8] __attribute__((aligned(16)));
        #pragma unroll
        for (int j = 0; j < 8; ++j) {
            const float x = tile[(f8l * 8 + j) * M + m];  // 2 lanes/bank: free
            const _Float16 h = (_Float16)x;               // RNE
            hh[j] = __builtin_bit_cast(u16, h);
        }
        *(uint4*)&hT[obase + (size_t)idx * 8] = *(const uint4*)hh;
    }
}

// ---------------------------------------------------------------------------
// ROUND 17: MORE CONCURRENT BLOCKS. Fitted invariant across r9-r16: each
// BLOCK sustains ~13-16 GB/s of staged global bytes regardless of wave count
// (4/8/16), phase structure, vmcnt discipline (r16 neutral), or cache level
// (r14 neutral). Per-CU rate = blocks/CU x ~14 GB/s (r9: 2 blocks -> 29.8
// GB/s/CU -- no cap at 14). All schedule families are exhausted; the one
// untested lever is MORE BLOCK SLOTS PER CU.
// THIS ROUND: 1 block = ONE (a,b) Gram matrix, 4 waves x 64x64 output ->
// acc = 64 AGPR, ~50 VGPR -> 4 waves/SIMD (__launch_bounds__(256,4)) ->
// 4 blocks/CU (LDS 32 KB: A+B K=32 chunks double-buffered; 4x32=128<=160).
// Both A and B staged via LDS (2x wave reuse each). Grid 4160 = 2 mats x
// 2080 pairs = 8 XCDs x 520 (pinning kept). Bytes 532 MB (+31% vs r9 --
// no pair-sharing) but 2x block slots: per-block-chain model predicts
// 128KB / 14GB/s x 4.06 rounds ~= 36-42 us; a hidden per-CU cap at ~30
// GB/s predicts ~69 us. Decisive test. Reg-staging (NOT global_load_lds:
// r15 showed __syncthreads drains the DMA -> zero effective prefetch).
// Diagonal blocks (a==b) stage B=A redundantly (64/4160 = 1.5%, uniform).
// ---------------------------------------------------------------------------

__global__ __launch_bounds__(256, 4) void gram_hist_mfma(
    const u16* __restrict__ hT, float* __restrict__ out)
{
    // [buf 0..1][A 4096 | B 4096] u16 = 32 KB.
    __shared__ u16 lds[2 * 8192];
    __shared__ float smin[4], smax[4];
    __shared__ int hist[8];

    const int tid  = threadIdx.x;
    const int lane = tid & 63;
    const int w    = tid >> 6;       // 0..3

    if (tid < 8) hist[tid] = 0;

    // XCD pinning: 4160 = 8 * 520. xcd = bid & 7 (HW round-robin);
    // mats split 4+4; pair index p = (xcd&3)*520 + bid>>3 in [0,2080).
    const int bid = blockIdx.x;
    const int xcd = bid & 7;
    const int mat = xcd >> 2;
    int p = (xcd & 3) * 520 + (bid >> 3);
    // Decode p -> (a, b), a-major upper triangle incl diagonal (count 64-a).
    int a = 0;
    { int cnt = 64; while (p >= cnt) { p -= cnt; ++a; --cnt; } }
    const int b = a + p;

    const int qr = w >> 1;           // 64-row half (A window)
    const int qc = w & 1;            // 64-col half (B window)
    const int l31   = lane & 31;
    const int lhalf = lane >> 5;

    // Staging: per chunk (K=32) A is 4096 u16, B is 4096 u16.
    // Thread t copies A granules {t, 256+t} and B granules {t, 256+t}.
    const u16* pa = hT + (size_t)(mat * BS + a) * MF + tid * 8;
    const u16* pb = hT + (size_t)(mat * BS + b) * MF + tid * 8;
    const int dA0 = tid * 8;                 // + buf
    const int dA1 = 2048 + tid * 8;
    const int dB0 = 4096 + tid * 8;
    const int dB1 = 4096 + 2048 + tid * 8;

    f32x16 acc[2][2];
    #pragma unroll
    for (int t = 0; t < 2; ++t)
        #pragma unroll
        for (int u = 0; u < 2; ++u)
            #pragma unroll
            for (int r = 0; r < 16; ++r) acc[t][u][r] = 0.0f;

    uint4 rA0, rA1, rB0, rB1;

    // ---- prologue: chunk 0 -> buf0 ----
    rA0 = *(const uint4*)(pa);
    rA1 = *(const uint4*)(pa + 2048);
    rB0 = *(const uint4*)(pb);
    rB1 = *(const uint4*)(pb + 2048);
    *(uint4*)&lds[dA0] = rA0;
    *(uint4*)&lds[dA1] = rA1;
    *(uint4*)&lds[dB0] = rB0;
    *(uint4*)&lds[dB1] = rB1;
    __syncthreads();

    // ---- 8 chunks, double-buffered, register prefetch (r9 pattern) ----
    #pragma unroll
    for (int s = 0; s < 8; ++s) {
        const int cur = (s & 1) * 8192;
        const int alt = cur ^ 8192;

        if (s < 7) {   // global->VGPR for chunk s+1; MFMA phase covers latency
            const int koff = (s + 1) * 4096;
            rA0 = *(const uint4*)(pa + koff);
            rA1 = *(const uint4*)(pa + koff + 2048);
            rB0 = *(const uint4*)(pb + koff);
            rB1 = *(const uint4*)(pb + koff + 2048);
        }

        // 8 MFMAs: kk = 0,1 (K=16 halves); 2x2 fragment grid.
        #pragma unroll
        for (int kk = 0; kk < 2; ++kk) {
            const int kb = cur + kk * 2048 + lhalf * 1024;
            f16x8 af[2], bf[2];
            af[0] = *(const f16x8*)&lds[kb + qr * 512 + l31 * 8];
            af[1] = *(const f16x8*)&lds[kb + qr * 512 + 256 + l31 * 8];
            bf[0] = *(const f16x8*)&lds[kb + 4096 + qc * 512 + l31 * 8];
            bf[1] = *(const f16x8*)&lds[kb + 4096 + qc * 512 + 256 + l31 * 8];
            acc[0][0] = __builtin_amdgcn_mfma_f32_32x32x16_f16(af[0], bf[0], acc[0][0], 0, 0, 0);
            acc[0][1] = __builtin_amdgcn_mfma_f32_32x32x16_f16(af[0], bf[1], acc[0][1], 0, 0, 0);
            acc[1][0] = __builtin_amdgcn_mfma_f32_32x32x16_f16(af[1], bf[0], acc[1][0], 0, 0, 0);
            acc[1][1] = __builtin_amdgcn_mfma_f32_32x32x16_f16(af[1], bf[1], acc[1][1], 0, 0, 0);
        }

        if (s < 7) {
            *(uint4*)&lds[alt + dA0] = rA0;
            *(uint4*)&lds[alt + dA1] = rA1;
            *(uint4*)&lds[alt + dB0] = rB0;
            *(uint4*)&lds[alt + dB1] = rB1;
        }
        __syncthreads();
    }

    // ---- epilogue: single matrix, 4 waves ----
    float vmin = acc[0][0][0], vmax = vmin;
    #pragma unroll
    for (int t = 0; t < 2; ++t)
        #pragma unroll
        for (int u = 0; u < 2; ++u)
            #pragma unroll
            for (int r = 0; r < 16; ++r) {
                vmin = fminf(vmin, acc[t][u][r]);
                vmax = fmaxf(vmax, acc[t][u][r]);
            }
    #pragma unroll
    for (int off = 1; off < 64; off <<= 1) {
        vmin = fminf(vmin, __shfl_xor(vmin, off, 64));
        vmax = fmaxf(vmax, __shfl_xor(vmax, off, 64));
    }
    if (lane == 0) { smin[w] = vmin; smax[w] = vmax; }
    __syncthreads();
    const float pmn = fminf(fminf(smin[0], smin[1]), fminf(smin[2], smin[3]));
    const float pmx = fmaxf(fmaxf(smax[0], smax[1]), fmaxf(smax[2], smax[3]));
    const float denom = (pmx > pmn) ? (pmx - pmn) : 1.0f;
    const float scale = 8.0f / denom;
    const float bias  = -pmn * scale;

    // per-thread packed histogram: 64 values -> 8-bit fields (<=64/bin)
    unsigned w0 = 0, w1 = 0;
    #pragma unroll
    for (int t = 0; t < 2; ++t)
        #pragma unroll
        for (int u = 0; u < 2; ++u)
            #pragma unroll
            for (int r = 0; r < 16; ++r) {
                const float tv = fmaf(acc[t][u][r], scale, bias);
                int k = (int)tv;         // tv >= -eps; trunc == floor
                k = k > 7 ? 7 : k;
                const unsigned inc = 1u << ((k & 3) * 8);
                if (k < 4) w0 += inc; else w1 += inc;
            }
    unsigned e0 = (w0 & 0xFFu)         | (((w0 >> 8)  & 0xFFu) << 16);
    unsigned e1 = ((w0 >> 16) & 0xFFu) | (((w0 >> 24) & 0xFFu) << 16);
    unsigned e2 = (w1 & 0xFFu)         | (((w1 >> 8)  & 0xFFu) << 16);
    unsigned e3 = ((w1 >> 16) & 0xFFu) | (((w1 >> 24) & 0xFFu) << 16);
    #pragma unroll
    for (int off = 32; off > 0; off >>= 1) {
        e0 += __shfl_down(e0, off, 64);
        e1 += __shfl_down(e1, off, 64);
        e2 += __shfl_down(e2, off, 64);
        e3 += __shfl_down(e3, off, 64);
    }
    if (lane == 0) {
        atomicAdd(&hist[0], (int)(e0 & 0xFFFFu)); atomicAdd(&hist[1], (int)(e0 >> 16));
        atomicAdd(&hist[2], (int)(e1 & 0xFFFFu)); atomicAdd(&hist[3], (int)(e1 >> 16));
        atomicAdd(&hist[4], (int)(e2 & 0xFFFFu)); atomicAdd(&hist[5], (int)(e2 >> 16));
        atomicAdd(&hist[6], (int)(e3 & 0xFFFFu)); atomicAdd(&hist[7], (int)(e3 >> 16));
    }
    __syncthreads();

    // wave 0 normalizes and writes both symmetric rows.
    if (w == 0 && lane < 8) {
        float ss = 0.0f;
        #pragma unroll
        for (int k = 0; k < 8; ++k) {
            const float cc = (float)hist[k];
            ss += cc * cc;
        }
        const float nrm = fmaxf(sqrtf(ss), 1e-12f);
        const float v = (float)hist[lane] / nrm;
        out[((size_t)a * BS + b) * 16 + mat * 8 + lane] = v;
        if (a != b)
            out[((size_t)b * BS + a) * 16 + mat * 8 + lane] = v;
    }
}

extern "C" void kernel_launch(void* const* d_in, const int* in_sizes, int n_in,
                              void* d_out, int out_size, void* d_ws, size_t ws_size,
                              hipStream_t stream) {
    const float* m1 = (const float*)d_in[0];
    const float* m2 = (const float*)d_in[1];
    float* out = (float*)d_out;

    // Workspace: granule-major fp16 array, 2*64*128*256 u16 = 8.39 MB.
    u16* hT = (u16*)d_ws;

    convert_f16_kernel<<<dim3(128, 4), 256, 0, stream>>>(m1, m2, hT);
    gram_hist_mfma<<<2 * NPAIR, 256, 0, stream>>>(hT, out);
}